// Round 2
// baseline (2217.038 us; speedup 1.0000x reference)
//
#include <hip/hip_runtime.h>
#include <stdint.h>

// GRU: B=64, T=1024, I=256, H=256, fp32 in/out, bf16 MFMA compute.
// k_prep: fragmentize 6 weight mats into MFMA B-frag layout; fold biases.
// k_proj: x_m = X@W_m + b'_m (m=z,r pre-scaled by -log2(e)); A-frags read
//         straight from global (no LDS), af in regs, m-outer acc reuse.
// k_rnn : 4 blocks x 512 thr; 16 batches/block; Uz,Ur B-frags in AGPRs,
//         Uh in LDS; per step: MFMA(n2=0) -> [MFMA(n2=1) || gates(n2=0)]
//         -> gates(n2=1); sched_group_barrier-enforced interleave.

typedef float  f32x4 __attribute__((ext_vector_type(4)));
typedef short  s16x8 __attribute__((ext_vector_type(8)));
typedef unsigned short u16;
typedef unsigned long long u64c;

#define MFMA_BF16(a, b, c) __builtin_amdgcn_mfma_f32_16x16x32_bf16((a), (b), (c), 0, 0, 0)
#define L2E 1.4426950408889634f

static __device__ __forceinline__ u16 f2bf(float f) {
  uint32_t u = __float_as_uint(f);
  u += 0x7FFFu + ((u >> 16) & 1u);   // RNE
  return (u16)(u >> 16);
}
static __device__ __forceinline__ uint32_t cvt_pk_bf16(float lo, float hi) {
  uint32_t r;
  asm("v_cvt_pk_bf16_f32 %0, %1, %2" : "=v"(r) : "v"(lo), "v"(hi));
  return r;
}
static __device__ __forceinline__ float fast_exp2(float x) {
#if __has_builtin(__builtin_amdgcn_exp2f)
  return __builtin_amdgcn_exp2f(x);
#else
  return exp2f(x);
#endif
}
static __device__ __forceinline__ float fast_rcp(float x) {
#if __has_builtin(__builtin_amdgcn_rcpf)
  return __builtin_amdgcn_rcpf(x);
#else
  return 1.0f / x;
#endif
}
static __device__ __forceinline__ float tanh_(float x) {
  float ax = fabsf(x);
  float e  = fast_exp2(-2.885390081777927f * ax);   // exp(-2|x|)
  float r  = (1.0f - e) * fast_rcp(1.0f + e);
  return x < 0.0f ? -r : r;
}

// ---- ws layout (bytes) ----
// [0, 786432)          : 6 mats x 8kk x 16n x 64lane x 16B bf16 B-fragments
// [786432, 789504)     : folded biases, 3 x 256 fp32 (unscaled)
// [1MiB, 1MiB + 96MiB) : x projections bf16, [m][t][g][n][lane][j] 8B chunks
#define WS_BIAS_OFF  786432
#define WS_X_OFF     (1u << 20)

// Fragment convention: kappa(l,i) = (l>>4)*8 + i.
// B-frag (mat,kk,n): lane l slot i = M[32kk + kappa(l,i)][16n + (l&15)]
// A-frag (kk):       lane l slot i = A[l&15][32kk + kappa(l,i)]
// C/D: col = lane&15, row = (lane>>4)*4 + reg   [m89]

__global__ __launch_bounds__(256) void k_prep(
    const float* __restrict__ Wz, const float* __restrict__ Wr, const float* __restrict__ Wh,
    const float* __restrict__ Uz, const float* __restrict__ Ur, const float* __restrict__ Uh,
    const float* __restrict__ bz, const float* __restrict__ br, const float* __restrict__ bh,
    const float* __restrict__ cz, const float* __restrict__ cr, const float* __restrict__ ch,
    u16* __restrict__ wfrag, float* __restrict__ wbias)
{
  if (blockIdx.x == 192) {   // bias fold block
    int c = threadIdx.x;
    wbias[c]       = bz[c] + cz[c];
    wbias[256 + c] = br[c] + cr[c];
    wbias[512 + c] = bh[c];
    return;
  }
  int tid = blockIdx.x * 256 + threadIdx.x;      // 0..49151
  int mat = tid >> 13;                           // 6 mats x 8192 threads
  int kk  = (tid >> 10) & 7;
  int n   = (tid >> 6) & 15;
  int l   = tid & 63;
  const float* M = (mat == 0) ? Wz : (mat == 1) ? Wr : (mat == 2) ? Wh
                 : (mat == 3) ? Uz : (mat == 4) ? Ur : Uh;
  int col   = n * 16 + (l & 15);
  int kbase = kk * 32 + (l >> 4) * 8;
  uint32_t d[4];
#pragma unroll
  for (int p = 0; p < 4; ++p) {
    u16 lo = f2bf(M[(kbase + 2 * p    ) * 256 + col]);
    u16 hi = f2bf(M[(kbase + 2 * p + 1) * 256 + col]);
    d[p] = (uint32_t)lo | ((uint32_t)hi << 16);
  }
  uint32_t* dst = (uint32_t*)(wfrag + ((size_t)mat * 65536 + (size_t)((kk * 16 + n) * 64 + l) * 8));
  dst[0] = d[0]; dst[1] = d[1]; dst[2] = d[2]; dst[3] = d[3];
}

__global__ __launch_bounds__(256) void k_proj(
    const float* __restrict__ X, const u16* __restrict__ wfrag,
    const float* __restrict__ wbias, u16* __restrict__ xout)
{
  const int t   = blockIdx.x;
  const int tid = threadIdx.x;
  const int l   = tid & 63;
  const int w   = tid >> 6;        // wave = batch group (M-tile)

  // A-fragments straight from global: row b = 16w + (l&15), k = 32kk + (l>>4)*8 + i
  const float* xrow = X + ((size_t)(w * 16 + (l & 15)) * 1024 + t) * 256 + (l >> 4) * 8;
  s16x8 af[8];
#pragma unroll
  for (int kk = 0; kk < 8; ++kk) {
    f32x4 a0 = *(const f32x4*)(xrow + kk * 32);
    f32x4 a1 = *(const f32x4*)(xrow + kk * 32 + 4);
    union { uint32_t d[4]; s16x8 v; } U;
    U.d[0] = cvt_pk_bf16(a0[0], a0[1]);
    U.d[1] = cvt_pk_bf16(a0[2], a0[3]);
    U.d[2] = cvt_pk_bf16(a1[0], a1[1]);
    U.d[3] = cvt_pk_bf16(a1[2], a1[3]);
    af[kk] = U.v;
  }

  const s16x8* WB = (const s16x8*)wfrag;
  const int g = w;
#pragma unroll
  for (int m = 0; m < 3; ++m) {
    f32x4 acc[16];
#pragma unroll
    for (int n = 0; n < 16; ++n) acc[n] = 0.0f;
#pragma unroll
    for (int kk = 0; kk < 8; ++kk) {
#pragma unroll
      for (int n = 0; n < 16; ++n) {
        s16x8 bf = WB[(size_t)m * 8192 + (kk * 16 + n) * 64 + l];
        acc[n] = MFMA_BF16(af[kk], bf, acc[n]);
      }
    }
    const float scale = (m < 2) ? -L2E : 1.0f;   // pre-scale z,r by -log2(e)
#pragma unroll
    for (int n = 0; n < 16; ++n) {
      int col = n * 16 + (l & 15);
      float b = wbias[m * 256 + col];
      float v0 = (acc[n][0] + b) * scale;
      float v1 = (acc[n][1] + b) * scale;
      float v2 = (acc[n][2] + b) * scale;
      float v3 = (acc[n][3] + b) * scale;
      uint32_t w0 = cvt_pk_bf16(v0, v1);
      uint32_t w1 = cvt_pk_bf16(v2, v3);
      size_t idx = ((((size_t)m * 1024 + t) * 4 + g) * 16 + n) * 64 + l;
      ((uint64_t*)xout)[idx] = (uint64_t)w0 | ((uint64_t)w1 << 32);
    }
  }
}

// Gate math: xz,xr arrive pre-scaled by -log2(e); xh plain.
#define GATE(N2, J, AZ, AR, AH, XV0, XV1, XV2, HN) do {                         \
  uint32_t dz_ = (uint32_t)((XV0) >> (((J) >> 1) * 32));                        \
  uint32_t dr_ = (uint32_t)((XV1) >> (((J) >> 1) * 32));                        \
  uint32_t dh_ = (uint32_t)((XV2) >> (((J) >> 1) * 32));                        \
  float xz_ = __uint_as_float(((J) & 1) ? (dz_ & 0xffff0000u) : (dz_ << 16));   \
  float xr_ = __uint_as_float(((J) & 1) ? (dr_ & 0xffff0000u) : (dr_ << 16));   \
  float xh_ = __uint_as_float(((J) & 1) ? (dh_ & 0xffff0000u) : (dh_ << 16));   \
  float z_  = fast_rcp(1.0f + fast_exp2(fmaf((AZ)[J], -L2E, xz_)));             \
  float rg_ = fast_rcp(1.0f + fast_exp2(fmaf((AR)[J], -L2E, xr_)));             \
  float th_ = tanh_(fmaf(rg_, (AH)[J] + chv[N2], xh_));                         \
  HN = fmaf(z_, hp[N2][J] - th_, th_);                                          \
  hp[N2][J] = HN;                                                               \
  op[J][(N2) * 16] = HN;                                                        \
} while (0)

#define SGB __builtin_amdgcn_sched_group_barrier

__global__ __launch_bounds__(512) void k_rnn(
    const u16* __restrict__ wfrag, const u16* __restrict__ xin,
    const float* __restrict__ h0, const float* __restrict__ ch,
    float* __restrict__ out)
{
  __shared__ __align__(16) u16 UhF[8 * 16 * 64 * 8];  // 128 KiB Uh fragments
  __shared__ __align__(16) u16 hb[2][4096];           // 2 x 8 KiB h A-frags
  const int g   = blockIdx.x;      // batch group: batches 16g..16g+15
  const int tid = threadIdx.x;
  const int l   = tid & 63;
  const int w   = tid >> 6;        // wave 0..7 owns cols [32w, 32w+32)

  const s16x8* WB = (const s16x8*)wfrag;

  // Uz, Ur register fragments: [n2][kk]
  s16x8 BZ[2][8], BR[2][8];
#pragma unroll
  for (int n2 = 0; n2 < 2; ++n2) {
    int n = w * 2 + n2;
#pragma unroll
    for (int kk = 0; kk < 8; ++kk) {
      BZ[n2][kk] = WB[(size_t)3 * 8192 + (kk * 16 + n) * 64 + l];
      BR[n2][kk] = WB[(size_t)4 * 8192 + (kk * 16 + n) * 64 + l];
    }
  }
  // Uh -> LDS (same fragment layout)
  s16x8* UhV = (s16x8*)UhF;
#pragma unroll
  for (int c = 0; c < 16; ++c) {
    int idx = c * 512 + tid;
    UhV[idx] = WB[(size_t)5 * 8192 + idx];
  }

  // h0 (fp32 master in regs, D-frag layout) + ch
  float hp[2][4];
  float chv[2];
#pragma unroll
  for (int n2 = 0; n2 < 2; ++n2) {
    int col = w * 32 + n2 * 16 + (l & 15);
    chv[n2] = ch[col];
#pragma unroll
    for (int j = 0; j < 4; ++j) {
      int b = g * 16 + (l >> 4) * 4 + j;
      hp[n2][j] = h0[b * 256 + col];
    }
  }
  // seed hb[0]
#pragma unroll
  for (int n2 = 0; n2 < 2; ++n2) {
    int cb = 2 * n2 + ((l >> 3) & 1);
#pragma unroll
    for (int j = 0; j < 4; ++j) {
      int rr = (l >> 4) * 4 + j;
      hb[0][w * 512 + (rr + 16 * cb) * 8 + (l & 7)] = f2bf(hp[n2][j]);
    }
  }
  __syncthreads();

  // strength-reduced pointers
  const uint64_t* xp0 = (const uint64_t*)xin + ((size_t)0 * 4194304 + (g * 16 + 2 * w) * 64 + l);
  const uint64_t* xp1 = (const uint64_t*)xin + ((size_t)1 * 4194304 + (g * 16 + 2 * w) * 64 + l);
  const uint64_t* xp2 = (const uint64_t*)xin + ((size_t)2 * 4194304 + (g * 16 + 2 * w) * 64 + l);
  float* op[4];
#pragma unroll
  for (int j = 0; j < 4; ++j)
    op[j] = out + (size_t)(g * 16 + (l >> 4) * 4 + j) * 262144 + w * 32 + (l & 15);

  char* hbbase = (char*)&hb[0][0];
  const int wb_off = w * 1024 + ((l >> 4) * 4 + 16 * ((l >> 3) & 1)) * 16 + (l & 7) * 2;
  const char* Uh0 = (char*)UhF + (size_t)((2 * w) * 64 + l) * 16;   // n=2w, kk stride 16384B
  const char* Uh1 = Uh0 + 1024;                                     // n=2w+1
  int hoff = 0;

  for (int t = 0; t < 1024; ++t) {
    // x loads (consumed mid/late step; latency hidden under MFMA phase)
    uint64_t x0a = xp0[0], x0b = xp0[64];
    uint64_t x1a = xp1[0], x1b = xp1[64];
    uint64_t x2a = xp2[0], x2b = xp2[64];
    xp0 += 4096; xp1 += 4096; xp2 += 4096;

    const char* hbr = hbbase + hoff + l * 16;
    char* hbw = hbbase + (hoff ^ 8192) + wb_off;

    f32x4 az0 = 0.0f, ar0 = 0.0f, ah0 = 0.0f;
    // ---- phase A: MFMA for n2=0 ----
#pragma unroll
    for (int kk = 0; kk < 8; ++kk) {
      s16x8 a_ = *(const s16x8*)(hbr + kk * 1024);
      s16x8 u_ = *(const s16x8*)(Uh0 + kk * 16384);
      az0 = MFMA_BF16(a_, BZ[0][kk], az0);
      ar0 = MFMA_BF16(a_, BR[0][kk], ar0);
      ah0 = MFMA_BF16(a_, u_, ah0);
    }

    // ---- phase B: MFMA for n2=1 interleaved with gates(n2=0) ----
    f32x4 az1 = 0.0f, ar1 = 0.0f, ah1 = 0.0f;
    float hn0, hn1, hn2, hn3;
#pragma unroll
    for (int kk = 0; kk < 8; ++kk) {
      s16x8 a_ = *(const s16x8*)(hbr + kk * 1024);
      s16x8 u_ = *(const s16x8*)(Uh1 + kk * 16384);
      az1 = MFMA_BF16(a_, BZ[1][kk], az1);
      ar1 = MFMA_BF16(a_, BR[1][kk], ar1);
      ah1 = MFMA_BF16(a_, u_, ah1);
      if (kk == 1) { GATE(0, 0, az0, ar0, ah0, x0a, x1a, x2a, hn0); }
      if (kk == 3) {
        GATE(0, 1, az0, ar0, ah0, x0a, x1a, x2a, hn1);
        uint32_t pk_ = cvt_pk_bf16(hn0, hn1);
        *(u16*)(hbw +  0) = (u16)pk_;
        *(u16*)(hbw + 16) = (u16)(pk_ >> 16);
      }
      if (kk == 5) { GATE(0, 2, az0, ar0, ah0, x0a, x1a, x2a, hn2); }
      if (kk == 7) {
        GATE(0, 3, az0, ar0, ah0, x0a, x1a, x2a, hn3);
        uint32_t pk_ = cvt_pk_bf16(hn2, hn3);
        *(u16*)(hbw + 32) = (u16)pk_;
        *(u16*)(hbw + 48) = (u16)(pk_ >> 16);
      }
      SGB(0x100, 2, 0);  // 2 DS_READ
      SGB(0x008, 3, 0);  // 3 MFMA
      SGB(0x002, 16, 0); // 16 VALU
      SGB(0x040, 1, 0);  // 1 VMEM write
    }

    // ---- phase C: gates(n2=1) ----
    {
      float gn0, gn1, gn2, gn3;
      GATE(1, 0, az1, ar1, ah1, x0b, x1b, x2b, gn0);
      GATE(1, 1, az1, ar1, ah1, x0b, x1b, x2b, gn1);
      uint32_t pk_ = cvt_pk_bf16(gn0, gn1);
      *(u16*)(hbw + 512) = (u16)pk_;
      *(u16*)(hbw + 528) = (u16)(pk_ >> 16);
      GATE(1, 2, az1, ar1, ah1, x0b, x1b, x2b, gn2);
      GATE(1, 3, az1, ar1, ah1, x0b, x1b, x2b, gn3);
      uint32_t pk2_ = cvt_pk_bf16(gn2, gn3);
      *(u16*)(hbw + 544) = (u16)pk2_;
      *(u16*)(hbw + 560) = (u16)(pk2_ >> 16);
    }

#pragma unroll
    for (int j = 0; j < 4; ++j) op[j] += 256;
    hoff ^= 8192;
    __syncthreads();
  }

  // h_last
#pragma unroll
  for (int n2 = 0; n2 < 2; ++n2) {
    int col = w * 32 + n2 * 16 + (l & 15);
#pragma unroll
    for (int j = 0; j < 4; ++j) {
      int b = g * 16 + (l >> 4) * 4 + j;
      out[(size_t)64 * 1024 * 256 + (size_t)b * 256 + col] = hp[n2][j];
    }
  }
}

extern "C" void kernel_launch(void* const* d_in, const int* in_sizes, int n_in,
                              void* d_out, int out_size, void* d_ws, size_t ws_size,
                              hipStream_t stream) {
  const float* X  = (const float*)d_in[0];
  const float* h0 = (const float*)d_in[1];
  const float* Wz = (const float*)d_in[2];
  const float* Wr = (const float*)d_in[3];
  const float* Wh = (const float*)d_in[4];
  const float* bz = (const float*)d_in[5];
  const float* br = (const float*)d_in[6];
  const float* bh = (const float*)d_in[7];
  const float* Uz = (const float*)d_in[8];
  const float* Ur = (const float*)d_in[9];
  const float* Uh = (const float*)d_in[10];
  const float* cz = (const float*)d_in[11];
  const float* cr = (const float*)d_in[12];
  const float* ch = (const float*)d_in[13];

  char*  ws    = (char*)d_ws;
  u16*   wfrag = (u16*)ws;
  float* wbias = (float*)(ws + WS_BIAS_OFF);
  u16*   xbuf  = (u16*)(ws + WS_X_OFF);
  float* out   = (float*)d_out;

  k_prep<<<193, 256, 0, stream>>>(Wz, Wr, Wh, Uz, Ur, Uh, bz, br, bh, cz, cr, ch,
                                  wfrag, wbias);
  k_proj<<<1024, 256, 0, stream>>>(X, wfrag, wbias, xbuf);
  k_rnn<<<4, 512, 0, stream>>>(wfrag, xbuf, h0, ch, out);
}

// Round 3
// 1617.717 us; speedup vs baseline: 1.3705x; 1.3705x over previous
//
#include <hip/hip_runtime.h>
#include <stdint.h>

// GRU: B=64, T=1024, I=256, H=256, fp32 in/out, bf16 MFMA compute.
// k_prep: fragmentize 6 weight mats into MFMA B-frag layout; fold biases.
// k_proj: x_m = X@W_m + b'_m (z,r pre-scaled by -log2 e), D-frag 8B chunks.
// k_rnn : 16 blocks x 512 thr; 4 batches/block (rows 0-3 of the M=16 tile,
//         rows 4-15 zero). Uz,Ur B-frags in regs, Uh in LDS. After MFMA,
//         D-frags are redistributed wave-privately through LDS so every
//         lane computes exactly 2 gate outputs. One barrier per step.

typedef float  f32x4 __attribute__((ext_vector_type(4)));
typedef float  f32x2 __attribute__((ext_vector_type(2)));
typedef short  s16x8 __attribute__((ext_vector_type(8)));
typedef unsigned short u16;

#define MFMA_BF16(a, b, c) __builtin_amdgcn_mfma_f32_16x16x32_bf16((a), (b), (c), 0, 0, 0)
#define L2E 1.4426950408889634f

static __device__ __forceinline__ u16 f2bf(float f) {
  uint32_t u = __float_as_uint(f);
  u += 0x7FFFu + ((u >> 16) & 1u);   // RNE
  return (u16)(u >> 16);
}
static __device__ __forceinline__ uint32_t cvt_pk_bf16(float lo, float hi) {
  uint32_t r;
  asm("v_cvt_pk_bf16_f32 %0, %1, %2" : "=v"(r) : "v"(lo), "v"(hi));
  return r;
}
static __device__ __forceinline__ float fast_exp2(float x) {
#if __has_builtin(__builtin_amdgcn_exp2f)
  return __builtin_amdgcn_exp2f(x);
#else
  return exp2f(x);
#endif
}
static __device__ __forceinline__ float fast_rcp(float x) {
#if __has_builtin(__builtin_amdgcn_rcpf)
  return __builtin_amdgcn_rcpf(x);
#else
  return 1.0f / x;
#endif
}
static __device__ __forceinline__ float tanh_(float x) {
  float ax = fabsf(x);
  float e  = fast_exp2(-2.885390081777927f * ax);   // exp(-2|x|)
  float r  = (1.0f - e) * fast_rcp(1.0f + e);
  return x < 0.0f ? -r : r;
}

// ---- ws layout (bytes) ----
// [0, 786432)          : 6 mats x 8kk x 16n x 64lane x 16B bf16 B-fragments
// [786432, 789504)     : folded biases, 3 x 256 fp32 (unscaled)
// [1MiB, 1MiB + 96MiB) : x projections bf16, [m][t][g][n][lane] 8B chunks
#define WS_BIAS_OFF  786432
#define WS_X_OFF     (1u << 20)

// Fragment convention: kappa(l,i) = (l>>4)*8 + i.
// B-frag (mat,kk,n): lane l slot i = M[32kk + kappa(l,i)][16n + (l&15)]
// A-frag (kk):       lane l slot i = A[l&15][32kk + kappa(l,i)]
// C/D: col = lane&15, row = (lane>>4)*4 + reg   [m89]
// hb (A storage): value (row rr, col c) -> u16 index
//   (c>>5)*512 + (rr + 16*((c>>3)&3))*8 + (c&7)

__global__ __launch_bounds__(256) void k_prep(
    const float* __restrict__ Wz, const float* __restrict__ Wr, const float* __restrict__ Wh,
    const float* __restrict__ Uz, const float* __restrict__ Ur, const float* __restrict__ Uh,
    const float* __restrict__ bz, const float* __restrict__ br, const float* __restrict__ bh,
    const float* __restrict__ cz, const float* __restrict__ cr, const float* __restrict__ ch,
    u16* __restrict__ wfrag, float* __restrict__ wbias)
{
  if (blockIdx.x == 192) {   // bias fold block
    int c = threadIdx.x;
    wbias[c]       = bz[c] + cz[c];
    wbias[256 + c] = br[c] + cr[c];
    wbias[512 + c] = bh[c];
    return;
  }
  int tid = blockIdx.x * 256 + threadIdx.x;      // 0..49151
  int mat = tid >> 13;                           // 6 mats x 8192 threads
  int kk  = (tid >> 10) & 7;
  int n   = (tid >> 6) & 15;
  int l   = tid & 63;
  const float* M = (mat == 0) ? Wz : (mat == 1) ? Wr : (mat == 2) ? Wh
                 : (mat == 3) ? Uz : (mat == 4) ? Ur : Uh;
  int col   = n * 16 + (l & 15);
  int kbase = kk * 32 + (l >> 4) * 8;
  uint32_t d[4];
#pragma unroll
  for (int p = 0; p < 4; ++p) {
    u16 lo = f2bf(M[(kbase + 2 * p    ) * 256 + col]);
    u16 hi = f2bf(M[(kbase + 2 * p + 1) * 256 + col]);
    d[p] = (uint32_t)lo | ((uint32_t)hi << 16);
  }
  uint32_t* dst = (uint32_t*)(wfrag + ((size_t)mat * 65536 + (size_t)((kk * 16 + n) * 64 + l) * 8));
  dst[0] = d[0]; dst[1] = d[1]; dst[2] = d[2]; dst[3] = d[3];
}

__global__ __launch_bounds__(256) void k_proj(
    const float* __restrict__ X, const u16* __restrict__ wfrag,
    const float* __restrict__ wbias, u16* __restrict__ xout)
{
  const int t   = blockIdx.x;
  const int tid = threadIdx.x;
  const int l   = tid & 63;
  const int w   = tid >> 6;        // wave = batch group (M-tile)

  // A-fragments straight from global: row b = 16w + (l&15), k = 32kk + (l>>4)*8 + i
  const float* xrow = X + ((size_t)(w * 16 + (l & 15)) * 1024 + t) * 256 + (l >> 4) * 8;
  s16x8 af[8];
#pragma unroll
  for (int kk = 0; kk < 8; ++kk) {
    f32x4 a0 = *(const f32x4*)(xrow + kk * 32);
    f32x4 a1 = *(const f32x4*)(xrow + kk * 32 + 4);
    union { uint32_t d[4]; s16x8 v; } U;
    U.d[0] = cvt_pk_bf16(a0[0], a0[1]);
    U.d[1] = cvt_pk_bf16(a0[2], a0[3]);
    U.d[2] = cvt_pk_bf16(a1[0], a1[1]);
    U.d[3] = cvt_pk_bf16(a1[2], a1[3]);
    af[kk] = U.v;
  }

  const s16x8* WB = (const s16x8*)wfrag;
  const int g = w;
#pragma unroll
  for (int m = 0; m < 3; ++m) {
    f32x4 acc[16];
#pragma unroll
    for (int n = 0; n < 16; ++n) acc[n] = 0.0f;
#pragma unroll
    for (int kk = 0; kk < 8; ++kk) {
#pragma unroll
      for (int n = 0; n < 16; ++n) {
        s16x8 bf = WB[(size_t)m * 8192 + (kk * 16 + n) * 64 + l];
        acc[n] = MFMA_BF16(af[kk], bf, acc[n]);
      }
    }
    const float scale = (m < 2) ? -L2E : 1.0f;   // pre-scale z,r by -log2(e)
#pragma unroll
    for (int n = 0; n < 16; ++n) {
      int col = n * 16 + (l & 15);
      float b = wbias[m * 256 + col];
      float v0 = (acc[n][0] + b) * scale;
      float v1 = (acc[n][1] + b) * scale;
      float v2 = (acc[n][2] + b) * scale;
      float v3 = (acc[n][3] + b) * scale;
      uint32_t w0 = cvt_pk_bf16(v0, v1);
      uint32_t w1 = cvt_pk_bf16(v2, v3);
      size_t idx = ((((size_t)m * 1024 + t) * 4 + g) * 16 + n) * 64 + l;
      ((uint64_t*)xout)[idx] = (uint64_t)w0 | ((uint64_t)w1 << 32);
    }
  }
}

__global__ __launch_bounds__(512) void k_rnn(
    const u16* __restrict__ wfrag, const u16* __restrict__ xin,
    const float* __restrict__ h0, const float* __restrict__ ch,
    float* __restrict__ out)
{
  __shared__ __align__(16) u16 UhF[8 * 16 * 64 * 8];   // 128 KiB Uh fragments
  __shared__ __align__(16) u16 hb[2][4096];            // 16 KiB h A-frags (dbuf)
  __shared__ __align__(16) float G[8][3][2][16][4];    // 12 KiB wave-private D redistribution

  const int blk = blockIdx.x;           // 0..15 ; batches [4*blk, 4*blk+4)
  const int g   = blk >> 2;             // old 16-batch group (xbuf layout)
  const int q   = blk & 3;              // quarter within group
  const int tid = threadIdx.x;
  const int l   = tid & 63;
  const int w   = tid >> 6;             // wave 0..7 owns cols [32w, 32w+32)

  const int col16 = l & 15;
  const int b4    = (l >> 4) & 1;
  const int n2g   = l >> 5;             // this lane's gate n2 (0 or 1)
  const int r4    = 2 * b4;             // first of this lane's 2 local rows
  const int cgate = w * 32 + n2g * 16 + col16;   // global col of gate outputs

  const s16x8* WB = (const s16x8*)wfrag;

  // Uz, Ur register fragments: [n2][kk]
  s16x8 BZ[2][8], BR[2][8];
#pragma unroll
  for (int n2 = 0; n2 < 2; ++n2) {
    int n = w * 2 + n2;
#pragma unroll
    for (int kk = 0; kk < 8; ++kk) {
      BZ[n2][kk] = WB[(size_t)3 * 8192 + (kk * 16 + n) * 64 + l];
      BR[n2][kk] = WB[(size_t)4 * 8192 + (kk * 16 + n) * 64 + l];
    }
  }
  // Uh -> LDS (same fragment layout)
  s16x8* UhV = (s16x8*)UhF;
#pragma unroll
  for (int c = 0; c < 16; ++c) {
    int idx = c * 512 + tid;
    UhV[idx] = WB[(size_t)5 * 8192 + idx];
  }

  // zero both hb buffers (rows 4-15 stay zero forever)
  {
    uint32_t* hz = (uint32_t*)&hb[0][0];
#pragma unroll
    for (int c = 0; c < 8; ++c) hz[c * 512 + tid] = 0;
  }
  __syncthreads();

  // h master (fp32) for this lane's 2 outputs + ch
  const float chv = ch[cgate];
  float hp0 = h0[(size_t)(4 * blk + r4    ) * 256 + cgate];
  float hp1 = h0[(size_t)(4 * blk + r4 + 1) * 256 + cgate];

  // hb write address (bytes): canonical u16 idx = w*512 + (rr + 16*(2*n2g + (col16>>3)))*8 + (col16&7)
  char* hbbase = (char*)&hb[0][0];
  const int hbw_off = (w * 512 + (16 * (2 * n2g + (col16 >> 3)) + r4) * 8 + (col16 & 7)) * 2;

  // seed hb[0] rows 0-3
  {
    uint32_t pk = cvt_pk_bf16(hp0, hp1);
    *(u16*)(hbbase + hbw_off     ) = (u16)pk;
    *(u16*)(hbbase + hbw_off + 16) = (u16)(pk >> 16);
  }
  __syncthreads();

  // strength-reduced pointers
  const int xlane = 16 * q + col16;
  const int n_g   = 2 * w + n2g;
  const uint64_t* xp0 = (const uint64_t*)xin + ((((size_t)0 * 1024) * 4 + g) * 16 + n_g) * 64 + xlane;
  const uint64_t* xp1 = (const uint64_t*)xin + ((((size_t)1 * 1024) * 4 + g) * 16 + n_g) * 64 + xlane;
  const uint64_t* xp2 = (const uint64_t*)xin + ((((size_t)2 * 1024) * 4 + g) * 16 + n_g) * 64 + xlane;
  float* op0 = out + (size_t)(4 * blk + r4) * 262144 + cgate;
  float* op1 = op0 + 262144;

  const char* Uh0 = (char*)UhF + (size_t)((2 * w) * 64 + l) * 16;   // n=2w, kk stride 16384B
  const char* Uh1 = Uh0 + 1024;                                     // n=2w+1
  const int xsh = 32 * b4;
  int hoff = 0;

  for (int t = 0; t < 1024; ++t) {
    // x loads issued early (consumed after MFMA phase)
    uint64_t xv0 = *xp0, xv1 = *xp1, xv2 = *xp2;
    xp0 += 4096; xp1 += 4096; xp2 += 4096;

    const char* hbr = hbbase + hoff + l * 16;

    // ---- MFMA phase: 3 mats x 2 n2 x 8 kk ----
    f32x4 az[2], ar[2], ah[2];
#pragma unroll
    for (int n2 = 0; n2 < 2; ++n2) { az[n2] = 0.0f; ar[n2] = 0.0f; ah[n2] = 0.0f; }
#pragma unroll
    for (int kk = 0; kk < 8; ++kk) {
      s16x8 a_  = *(const s16x8*)(hbr + kk * 1024);
      s16x8 u0_ = *(const s16x8*)(Uh0 + kk * 16384);
      s16x8 u1_ = *(const s16x8*)(Uh1 + kk * 16384);
      az[0] = MFMA_BF16(a_, BZ[0][kk], az[0]);
      ar[0] = MFMA_BF16(a_, BR[0][kk], ar[0]);
      ah[0] = MFMA_BF16(a_, u0_, ah[0]);
      az[1] = MFMA_BF16(a_, BZ[1][kk], az[1]);
      ar[1] = MFMA_BF16(a_, BR[1][kk], ar[1]);
      ah[1] = MFMA_BF16(a_, u1_, ah[1]);
    }

    // ---- wave-private redistribution (lanes 0-15 hold real rows 0-3) ----
    if (l < 16) {
#pragma unroll
      for (int n2 = 0; n2 < 2; ++n2) {
        *(f32x2*)&G[w][0][n2][l][0] = f32x2{az[n2][0], az[n2][1]};
        *(f32x2*)&G[w][0][n2][l][2] = f32x2{az[n2][2], az[n2][3]};
        *(f32x2*)&G[w][1][n2][l][0] = f32x2{ar[n2][0], ar[n2][1]};
        *(f32x2*)&G[w][1][n2][l][2] = f32x2{ar[n2][2], ar[n2][3]};
        *(f32x2*)&G[w][2][n2][l][0] = f32x2{ah[n2][0], ah[n2][1]};
        *(f32x2*)&G[w][2][n2][l][2] = f32x2{ah[n2][2], ah[n2][3]};
      }
    }
    f32x2 vz = *(const f32x2*)&G[w][0][n2g][col16][r4];
    f32x2 vr = *(const f32x2*)&G[w][1][n2g][col16][r4];
    f32x2 vh = *(const f32x2*)&G[w][2][n2g][col16][r4];

    // ---- gates: 2 outputs per lane ----
    uint32_t dz = (uint32_t)(xv0 >> xsh);
    uint32_t dr = (uint32_t)(xv1 >> xsh);
    uint32_t dh = (uint32_t)(xv2 >> xsh);
    float xz0 = __uint_as_float(dz << 16), xz1 = __uint_as_float(dz & 0xffff0000u);
    float xr0 = __uint_as_float(dr << 16), xr1 = __uint_as_float(dr & 0xffff0000u);
    float xh0 = __uint_as_float(dh << 16), xh1 = __uint_as_float(dh & 0xffff0000u);

    float z0 = fast_rcp(1.0f + fast_exp2(fmaf(vz[0], -L2E, xz0)));
    float z1 = fast_rcp(1.0f + fast_exp2(fmaf(vz[1], -L2E, xz1)));
    float r0 = fast_rcp(1.0f + fast_exp2(fmaf(vr[0], -L2E, xr0)));
    float r1 = fast_rcp(1.0f + fast_exp2(fmaf(vr[1], -L2E, xr1)));
    float th0 = tanh_(fmaf(r0, vh[0] + chv, xh0));
    float th1 = tanh_(fmaf(r1, vh[1] + chv, xh1));
    float hn0 = fmaf(z0, hp0 - th0, th0);
    float hn1 = fmaf(z1, hp1 - th1, th1);
    hp0 = hn0; hp1 = hn1;

    // outputs + next-step A-frag
    *op0 = hn0; *op1 = hn1;
    op0 += 256; op1 += 256;
    {
      char* hbw = hbbase + (hoff ^ 8192) + hbw_off;
      uint32_t pk = cvt_pk_bf16(hn0, hn1);
      *(u16*)(hbw     ) = (u16)pk;
      *(u16*)(hbw + 16) = (u16)(pk >> 16);
    }

    hoff ^= 8192;
    __syncthreads();
  }

  // h_last
  out[(size_t)64 * 1024 * 256 + (size_t)(4 * blk + r4    ) * 256 + cgate] = hp0;
  out[(size_t)64 * 1024 * 256 + (size_t)(4 * blk + r4 + 1) * 256 + cgate] = hp1;
}

extern "C" void kernel_launch(void* const* d_in, const int* in_sizes, int n_in,
                              void* d_out, int out_size, void* d_ws, size_t ws_size,
                              hipStream_t stream) {
  const float* X  = (const float*)d_in[0];
  const float* h0 = (const float*)d_in[1];
  const float* Wz = (const float*)d_in[2];
  const float* Wr = (const float*)d_in[3];
  const float* Wh = (const float*)d_in[4];
  const float* bz = (const float*)d_in[5];
  const float* br = (const float*)d_in[6];
  const float* bh = (const float*)d_in[7];
  const float* Uz = (const float*)d_in[8];
  const float* Ur = (const float*)d_in[9];
  const float* Uh = (const float*)d_in[10];
  const float* cz = (const float*)d_in[11];
  const float* cr = (const float*)d_in[12];
  const float* ch = (const float*)d_in[13];

  char*  ws    = (char*)d_ws;
  u16*   wfrag = (u16*)ws;
  float* wbias = (float*)(ws + WS_BIAS_OFF);
  u16*   xbuf  = (u16*)(ws + WS_X_OFF);
  float* out   = (float*)d_out;

  k_prep<<<193, 256, 0, stream>>>(Wz, Wr, Wh, Uz, Ur, Uh, bz, br, bh, cz, cr, ch,
                                  wfrag, wbias);
  k_proj<<<1024, 256, 0, stream>>>(X, wfrag, wbias, xbuf);
  k_rnn<<<16, 512, 0, stream>>>(wfrag, xbuf, h0, ch, out);
}

// Round 4
// 1488.165 us; speedup vs baseline: 1.4898x; 1.0871x over previous
//
#include <hip/hip_runtime.h>
#include <stdint.h>

// GRU: B=64, T=1024, I=256, H=256, fp32 in/out, bf16 MFMA compute.
// k_prep: fragmentize 6 weight mats into MFMA B-frag layout; fold biases.
// k_proj: x_m = X@W_m + b'_m (z,r pre-scaled by -log2 e), D-frag 8B chunks.
// k_rnn : 16 blocks x 1024 thr (16 waves, 4/SIMD); 4 batches/block (rows 0-3
//         of the M=16 tile, rows 4-15 zero). Each wave owns ONE 16-col
//         n-tile: 24 MFMAs/step. Uz,Ur B-frags in regs (64 VGPR), Uh in LDS.
//         D-frags redistributed wave-privately through LDS so every lane
//         computes exactly ONE gate output. One light barrier per step
//         (lgkmcnt-only; out-stores stay in flight).

typedef float  f32x4 __attribute__((ext_vector_type(4)));
typedef short  s16x8 __attribute__((ext_vector_type(8)));
typedef unsigned short u16;

#define MFMA_BF16(a, b, c) __builtin_amdgcn_mfma_f32_16x16x32_bf16((a), (b), (c), 0, 0, 0)
#define L2E 1.4426950408889634f

static __device__ __forceinline__ u16 f2bf(float f) {
  uint32_t u = __float_as_uint(f);
  u += 0x7FFFu + ((u >> 16) & 1u);   // RNE
  return (u16)(u >> 16);
}
static __device__ __forceinline__ uint32_t cvt_pk_bf16(float lo, float hi) {
  uint32_t r;
  asm("v_cvt_pk_bf16_f32 %0, %1, %2" : "=v"(r) : "v"(lo), "v"(hi));
  return r;
}
static __device__ __forceinline__ float fast_exp2(float x) {
#if __has_builtin(__builtin_amdgcn_exp2f)
  return __builtin_amdgcn_exp2f(x);
#else
  return exp2f(x);
#endif
}
static __device__ __forceinline__ float fast_rcp(float x) {
#if __has_builtin(__builtin_amdgcn_rcpf)
  return __builtin_amdgcn_rcpf(x);
#else
  return 1.0f / x;
#endif
}
static __device__ __forceinline__ float tanh_(float x) {
  float ax = fabsf(x);
  float e  = fast_exp2(-2.885390081777927f * ax);   // exp(-2|x|)
  float r  = (1.0f - e) * fast_rcp(1.0f + e);
  return x < 0.0f ? -r : r;
}

// ---- ws layout (bytes) ----
// [0, 786432)          : 6 mats x 8kk x 16n x 64lane x 16B bf16 B-fragments
// [786432, 789504)     : folded biases, 3 x 256 fp32 (unscaled)
// [1MiB, 1MiB + 96MiB) : x projections bf16, [m][t][g][n][lane] 8B chunks
#define WS_BIAS_OFF  786432
#define WS_X_OFF     (1u << 20)

// Fragment convention: kappa(l,i) = (l>>4)*8 + i.
// B-frag (mat,kk,n): lane l slot i = M[32kk + kappa(l,i)][16n + (l&15)]
// A-frag (kk):       lane l slot i = A[l&15][32kk + kappa(l,i)]
// C/D: col = lane&15, row = (lane>>4)*4 + reg   [m89]
// hb (A storage): value (row rr, col c) -> u16 index
//   (c>>5)*512 + (rr + 16*((c>>3)&3))*8 + (c&7)

__global__ __launch_bounds__(256) void k_prep(
    const float* __restrict__ Wz, const float* __restrict__ Wr, const float* __restrict__ Wh,
    const float* __restrict__ Uz, const float* __restrict__ Ur, const float* __restrict__ Uh,
    const float* __restrict__ bz, const float* __restrict__ br, const float* __restrict__ bh,
    const float* __restrict__ cz, const float* __restrict__ cr, const float* __restrict__ ch,
    u16* __restrict__ wfrag, float* __restrict__ wbias)
{
  if (blockIdx.x == 192) {   // bias fold block
    int c = threadIdx.x;
    wbias[c]       = bz[c] + cz[c];
    wbias[256 + c] = br[c] + cr[c];
    wbias[512 + c] = bh[c];
    return;
  }
  int tid = blockIdx.x * 256 + threadIdx.x;      // 0..49151
  int mat = tid >> 13;                           // 6 mats x 8192 threads
  int kk  = (tid >> 10) & 7;
  int n   = (tid >> 6) & 15;
  int l   = tid & 63;
  const float* M = (mat == 0) ? Wz : (mat == 1) ? Wr : (mat == 2) ? Wh
                 : (mat == 3) ? Uz : (mat == 4) ? Ur : Uh;
  int col   = n * 16 + (l & 15);
  int kbase = kk * 32 + (l >> 4) * 8;
  uint32_t d[4];
#pragma unroll
  for (int p = 0; p < 4; ++p) {
    u16 lo = f2bf(M[(kbase + 2 * p    ) * 256 + col]);
    u16 hi = f2bf(M[(kbase + 2 * p + 1) * 256 + col]);
    d[p] = (uint32_t)lo | ((uint32_t)hi << 16);
  }
  uint32_t* dst = (uint32_t*)(wfrag + ((size_t)mat * 65536 + (size_t)((kk * 16 + n) * 64 + l) * 8));
  dst[0] = d[0]; dst[1] = d[1]; dst[2] = d[2]; dst[3] = d[3];
}

__global__ __launch_bounds__(256) void k_proj(
    const float* __restrict__ X, const u16* __restrict__ wfrag,
    const float* __restrict__ wbias, u16* __restrict__ xout)
{
  const int t   = blockIdx.x;
  const int tid = threadIdx.x;
  const int l   = tid & 63;
  const int w   = tid >> 6;        // wave = batch group (M-tile)

  // A-fragments straight from global: row b = 16w + (l&15), k = 32kk + (l>>4)*8 + i
  const float* xrow = X + ((size_t)(w * 16 + (l & 15)) * 1024 + t) * 256 + (l >> 4) * 8;
  s16x8 af[8];
#pragma unroll
  for (int kk = 0; kk < 8; ++kk) {
    f32x4 a0 = *(const f32x4*)(xrow + kk * 32);
    f32x4 a1 = *(const f32x4*)(xrow + kk * 32 + 4);
    union { uint32_t d[4]; s16x8 v; } U;
    U.d[0] = cvt_pk_bf16(a0[0], a0[1]);
    U.d[1] = cvt_pk_bf16(a0[2], a0[3]);
    U.d[2] = cvt_pk_bf16(a1[0], a1[1]);
    U.d[3] = cvt_pk_bf16(a1[2], a1[3]);
    af[kk] = U.v;
  }

  const s16x8* WB = (const s16x8*)wfrag;
  const int g = w;
#pragma unroll
  for (int m = 0; m < 3; ++m) {
    f32x4 acc[16];
#pragma unroll
    for (int n = 0; n < 16; ++n) acc[n] = 0.0f;
#pragma unroll
    for (int kk = 0; kk < 8; ++kk) {
#pragma unroll
      for (int n = 0; n < 16; ++n) {
        s16x8 bf = WB[(size_t)m * 8192 + (kk * 16 + n) * 64 + l];
        acc[n] = MFMA_BF16(af[kk], bf, acc[n]);
      }
    }
    const float scale = (m < 2) ? -L2E : 1.0f;   // pre-scale z,r by -log2(e)
#pragma unroll
    for (int n = 0; n < 16; ++n) {
      int col = n * 16 + (l & 15);
      float b = wbias[m * 256 + col];
      float v0 = (acc[n][0] + b) * scale;
      float v1 = (acc[n][1] + b) * scale;
      float v2 = (acc[n][2] + b) * scale;
      float v3 = (acc[n][3] + b) * scale;
      uint32_t w0 = cvt_pk_bf16(v0, v1);
      uint32_t w1 = cvt_pk_bf16(v2, v3);
      size_t idx = ((((size_t)m * 1024 + t) * 4 + g) * 16 + n) * 64 + l;
      ((uint64_t*)xout)[idx] = (uint64_t)w0 | ((uint64_t)w1 << 32);
    }
  }
}

__global__ __launch_bounds__(1024) void k_rnn(
    const u16* __restrict__ wfrag, const u16* __restrict__ xin,
    const float* __restrict__ h0, const float* __restrict__ ch,
    float* __restrict__ out)
{
  __shared__ __align__(16) u16 UhF[8 * 16 * 64 * 8];   // 128 KiB Uh fragments
  __shared__ __align__(16) u16 hb[2][4096];            // 16 KiB h A-frags (dbuf)
  __shared__ __align__(16) float G[16][3][16][4];      // 12 KiB wave-private D redistribution

  const int blk = blockIdx.x;           // 0..15 ; batches [4*blk, 4*blk+4)
  const int g   = blk >> 2;             // 16-batch group (xbuf layout)
  const int q   = blk & 3;              // quarter within group
  const int tid = threadIdx.x;
  const int l   = tid & 63;
  const int w   = tid >> 6;             // wave 0..15 owns cols [16w, 16w+16)

  const int col16 = l & 15;
  const int r4    = l >> 4;             // this lane's batch row 0..3
  const int cgate = w * 16 + col16;     // global col of this lane's gate output

  const s16x8* WB = (const s16x8*)wfrag;

  // Uz, Ur register fragments for n-tile w: [kk]
  s16x8 BZ[8], BR[8];
#pragma unroll
  for (int kk = 0; kk < 8; ++kk) {
    BZ[kk] = WB[(size_t)3 * 8192 + (kk * 16 + w) * 64 + l];
    BR[kk] = WB[(size_t)4 * 8192 + (kk * 16 + w) * 64 + l];
  }
  // Uh -> LDS (same fragment layout)
  s16x8* UhV = (s16x8*)UhF;
#pragma unroll
  for (int c = 0; c < 8; ++c) {
    int idx = c * 1024 + tid;
    UhV[idx] = WB[(size_t)5 * 8192 + idx];
  }

  // zero both hb buffers (rows 4-15 stay zero forever)
  {
    uint32_t* hz = (uint32_t*)&hb[0][0];
#pragma unroll
    for (int c = 0; c < 4; ++c) hz[c * 1024 + tid] = 0;
  }
  __syncthreads();

  // h master (fp32) for this lane's output + ch
  const float chv = ch[cgate];
  float hp = h0[(size_t)(4 * blk + r4) * 256 + cgate];

  // hb write byte offset for value (row r4, col cgate):
  //   u16 idx = (c>>5)*512 + (rr + 16*((c>>3)&3))*8 + (c&7)
  char* hbbase = (char*)&hb[0][0];
  const int hbw_off = (((w >> 1) * 512) +
                       (r4 + 16 * (((w & 1) << 1) | (col16 >> 3))) * 8 +
                       (col16 & 7)) * 2;

  // seed hb[0]
  *(u16*)(hbbase + hbw_off) = f2bf(hp);
  __syncthreads();

  // strength-reduced pointers
  const int xlane = 16 * q + col16;     // xbuf lane holding rows q*4..q*4+3
  const uint64_t* xp0 = (const uint64_t*)xin + ((((size_t)0 * 1024) * 4 + g) * 16 + w) * 64 + xlane;
  const uint64_t* xp1 = (const uint64_t*)xin + ((((size_t)1 * 1024) * 4 + g) * 16 + w) * 64 + xlane;
  const uint64_t* xp2 = (const uint64_t*)xin + ((((size_t)2 * 1024) * 4 + g) * 16 + w) * 64 + xlane;
  float* op = out + (size_t)(4 * blk + r4) * 262144 + cgate;

  const char* Uh0 = (char*)UhF + (size_t)(w * 64 + l) * 16;   // n=w, kk stride 16384B
  const int xsh = 16 * r4;
  int hoff = 0;

  for (int t = 0; t < 1024; ++t) {
    // x loads issued early (consumed after MFMA phase)
    uint64_t xv0 = *xp0, xv1 = *xp1, xv2 = *xp2;
    xp0 += 4096; xp1 += 4096; xp2 += 4096;

    const char* hbr = hbbase + hoff + l * 16;

    // ---- MFMA phase: 3 mats x 8 kk (one n-tile) ----
    f32x4 az = 0.0f, ar = 0.0f, ah = 0.0f;
#pragma unroll
    for (int kk = 0; kk < 8; ++kk) {
      s16x8 a_ = *(const s16x8*)(hbr + kk * 1024);
      s16x8 u_ = *(const s16x8*)(Uh0 + kk * 16384);
      az = MFMA_BF16(a_, BZ[kk], az);
      ar = MFMA_BF16(a_, BR[kk], ar);
      ah = MFMA_BF16(a_, u_, ah);
    }

    // ---- wave-private redistribution (lanes 0-15 hold real rows 0-3) ----
    if (l < 16) {
      *(f32x4*)&G[w][0][l][0] = az;
      *(f32x4*)&G[w][1][l][0] = ar;
      *(f32x4*)&G[w][2][l][0] = ah;
    }
    float vz = G[w][0][col16][r4];
    float vr = G[w][1][col16][r4];
    float vh = G[w][2][col16][r4];

    // ---- gate: 1 output per lane ----
    float xz = __uint_as_float((uint32_t)((xv0 >> xsh) << 16));
    float xr = __uint_as_float((uint32_t)((xv1 >> xsh) << 16));
    float xh = __uint_as_float((uint32_t)((xv2 >> xsh) << 16));

    float z  = fast_rcp(1.0f + fast_exp2(fmaf(vz, -L2E, xz)));
    float rg = fast_rcp(1.0f + fast_exp2(fmaf(vr, -L2E, xr)));
    float th = tanh_(fmaf(rg, vh + chv, xh));
    float hn = fmaf(z, hp - th, th);
    hp = hn;

    // next-step A-frag write, then output store (store stays in flight)
    *(u16*)(hbbase + (hoff ^ 8192) + hbw_off) = f2bf(hn);
    *op = hn;
    op += 256;

    hoff ^= 8192;
    // light barrier: LDS ordering only; do NOT drain vmcnt (out stores)
    asm volatile("s_waitcnt lgkmcnt(0)" ::: "memory");
    __builtin_amdgcn_s_barrier();
  }

  // h_last
  out[(size_t)64 * 1024 * 256 + (size_t)(4 * blk + r4) * 256 + cgate] = hp;
}

extern "C" void kernel_launch(void* const* d_in, const int* in_sizes, int n_in,
                              void* d_out, int out_size, void* d_ws, size_t ws_size,
                              hipStream_t stream) {
  const float* X  = (const float*)d_in[0];
  const float* h0 = (const float*)d_in[1];
  const float* Wz = (const float*)d_in[2];
  const float* Wr = (const float*)d_in[3];
  const float* Wh = (const float*)d_in[4];
  const float* bz = (const float*)d_in[5];
  const float* br = (const float*)d_in[6];
  const float* bh = (const float*)d_in[7];
  const float* Uz = (const float*)d_in[8];
  const float* Ur = (const float*)d_in[9];
  const float* Uh = (const float*)d_in[10];
  const float* cz = (const float*)d_in[11];
  const float* cr = (const float*)d_in[12];
  const float* ch = (const float*)d_in[13];

  char*  ws    = (char*)d_ws;
  u16*   wfrag = (u16*)ws;
  float* wbias = (float*)(ws + WS_BIAS_OFF);
  u16*   xbuf  = (u16*)(ws + WS_X_OFF);
  float* out   = (float*)d_out;

  k_prep<<<193, 256, 0, stream>>>(Wz, Wr, Wh, Uz, Ur, Uh, bz, br, bh, cz, cr, ch,
                                  wfrag, wbias);
  k_proj<<<1024, 256, 0, stream>>>(X, wfrag, wbias, xbuf);
  k_rnn<<<16, 1024, 0, stream>>>(wfrag, xbuf, h0, ch, out);
}